// Round 2
// baseline (876.758 us; speedup 1.0000x reference)
//
#include <hip/hip_runtime.h>
#include <cstdint>
#include <cstddef>

typedef __attribute__((ext_vector_type(8))) short short8;
typedef __attribute__((ext_vector_type(4))) float f32x4;

#define SCALE 0.17677669529663687f
#define KOFF 25165824UL
#define VOFF 50331648UL

__device__ __forceinline__ float bf2f(unsigned short u){
  union { unsigned int i; float f; } x; x.i = ((unsigned int)u) << 16; return x.f;
}
__device__ __forceinline__ unsigned short f2bf(float f){
  union { float f; unsigned int i; } x; x.f = f;
  unsigned int u = x.i;
  unsigned int r = u + 0x7fffu + ((u >> 16) & 1u);
  return (unsigned short)(r >> 16);
}

// Detect whether external float tensors are stored as bf16 (1) or fp32 (0).
// Probe even-indexed 16-bit halves of qkv: under fp32 these are mantissa-low
// bits (random exponent field); under bf16 they are genuine N(0,1) bf16s.
__device__ __forceinline__ int detect_bf16(const void* probe){
  const unsigned short* p = (const unsigned short*)probe;
  int ok = 1;
  #pragma unroll
  for (int i = 0; i < 32; i++){
    unsigned short u = p[2*i];
    int e = (u >> 7) & 0xFF;              // bf16 exponent field
    ok &= (e >= 0x60 && e <= 0x90) ? 1 : 0;
  }
  return ok;
}

__device__ __forceinline__ float ld1(const void* p, size_t i, int isbf){
  return isbf ? bf2f(((const unsigned short*)p)[i]) : ((const float*)p)[i];
}
// 8 consecutive elements starting at i (i % 8 == 0 at all call sites) -> bf16 frag
__device__ __forceinline__ short8 ld8(const void* p, size_t i, int isbf){
  short8 r;
  if (isbf){
    r = *(const short8*)((const unsigned short*)p + i);
  } else {
    const float4* f = (const float4*)((const float*)p + i);
    float4 u0 = f[0], u1 = f[1];
    r[0] = (short)f2bf(u0.x); r[1] = (short)f2bf(u0.y);
    r[2] = (short)f2bf(u0.z); r[3] = (short)f2bf(u0.w);
    r[4] = (short)f2bf(u1.x); r[5] = (short)f2bf(u1.y);
    r[6] = (short)f2bf(u1.z); r[7] = (short)f2bf(u1.w);
  }
  return r;
}
__device__ __forceinline__ void st1(void* p, size_t i, float v, int isbf){
  if (isbf) ((unsigned short*)p)[i] = f2bf(v);
  else      ((float*)p)[i] = v;
}

// ---------------- DynamicPosBias MLP: [465,2] -> [465,6] ----------------
__global__ void posmlp_kernel(const void* __restrict__ probe,
    const void* __restrict__ rpe,
    const void* __restrict__ w0, const void* __restrict__ b0,
    const void* __restrict__ g1, const void* __restrict__ be1,
    const void* __restrict__ w1, const void* __restrict__ bb1,
    const void* __restrict__ g2, const void* __restrict__ be2,
    const void* __restrict__ w2, const void* __restrict__ bb2,
    const void* __restrict__ g3, const void* __restrict__ be3,
    const void* __restrict__ w3, const void* __restrict__ bb3,
    float* __restrict__ pos_table)
{
  const int isbf = detect_bf16(probe);
  int r = blockIdx.x * blockDim.x + threadIdx.x;
  if (r >= 465) return;
  float x0 = ld1(rpe, 2*r, isbf), x1 = ld1(rpe, 2*r+1, isbf);
  float h[12], y[12];
  #pragma unroll
  for (int j=0;j<12;j++) h[j] = x0*ld1(w0,j,isbf) + x1*ld1(w0,12+j,isbf) + ld1(b0,j,isbf);

  // layer 1
  {
    float m=0.f;
    #pragma unroll
    for (int j=0;j<12;j++) m += h[j];
    m *= (1.f/12.f);
    float v=0.f;
    #pragma unroll
    for (int j=0;j<12;j++){ float d=h[j]-m; v += d*d; }
    v *= (1.f/12.f);
    float rs = 1.0f/sqrtf(v + 1e-5f);
    #pragma unroll
    for (int j=0;j<12;j++) y[j] = fmaxf((h[j]-m)*rs*ld1(g1,j,isbf) + ld1(be1,j,isbf), 0.f);
    #pragma unroll
    for (int j=0;j<12;j++){
      float s = ld1(bb1,j,isbf);
      #pragma unroll
      for (int i=0;i<12;i++) s += y[i]*ld1(w1,i*12+j,isbf);
      h[j] = s;
    }
  }
  // layer 2
  {
    float m=0.f;
    #pragma unroll
    for (int j=0;j<12;j++) m += h[j];
    m *= (1.f/12.f);
    float v=0.f;
    #pragma unroll
    for (int j=0;j<12;j++){ float d=h[j]-m; v += d*d; }
    v *= (1.f/12.f);
    float rs = 1.0f/sqrtf(v + 1e-5f);
    #pragma unroll
    for (int j=0;j<12;j++) y[j] = fmaxf((h[j]-m)*rs*ld1(g2,j,isbf) + ld1(be2,j,isbf), 0.f);
    #pragma unroll
    for (int j=0;j<12;j++){
      float s = ld1(bb2,j,isbf);
      #pragma unroll
      for (int i=0;i<12;i++) s += y[i]*ld1(w2,i*12+j,isbf);
      h[j] = s;
    }
  }
  // layer 3
  {
    float m=0.f;
    #pragma unroll
    for (int j=0;j<12;j++) m += h[j];
    m *= (1.f/12.f);
    float v=0.f;
    #pragma unroll
    for (int j=0;j<12;j++){ float d=h[j]-m; v += d*d; }
    v *= (1.f/12.f);
    float rs = 1.0f/sqrtf(v + 1e-5f);
    #pragma unroll
    for (int j=0;j<12;j++) y[j] = fmaxf((h[j]-m)*rs*ld1(g3,j,isbf) + ld1(be3,j,isbf), 0.f);
    #pragma unroll
    for (int o=0;o<6;o++){
      float s = ld1(bb3,o,isbf);
      #pragma unroll
      for (int i=0;i<12;i++) s += y[i]*ld1(w3,i*6+o,isbf);
      pos_table[r*6+o] = s;
    }
  }
}

// ---------------- gather: rpb[h][i][j] = pos_table[rel_idx[i][j]][h] ----------------
__global__ void gather_kernel(const int* __restrict__ rel_idx,
                              const float* __restrict__ pos_table,
                              float* __restrict__ rpb)
{
  int idx = blockIdx.x * blockDim.x + threadIdx.x;  // 16384
  int m = rel_idx[idx];
  #pragma unroll
  for (int h=0;h<6;h++) rpb[h*16384 + idx] = pos_table[m*6 + h];
}

// ---------------- pooled query: avg (c<96) / max (c>=96), *scale, bf16 out ----------------
__global__ void pool_kernel(const void* __restrict__ qkv,
                            unsigned short* __restrict__ poolq)
{
  const int isbf = detect_bf16(qkv);
  const int b = blockIdx.y;
  const int n = blockIdx.x;           // n = ph*16 + pw
  const int c = threadIdx.x;          // 0..191
  const int ph = n >> 4, pw = n & 15;
  // pooling cell covers h in [ph*16, ph*16+16), w in [pw*8, pw*8+8)
  const size_t base = ((size_t)(b*16384 + ph*16*128 + pw*8))*192 + c;
  float r;
  if (c < 96){
    float s = 0.f;
    for (int hi=0; hi<16; hi++)
      #pragma unroll
      for (int wi=0; wi<8; wi++)
        s += ld1(qkv, base + (size_t)(hi*128 + wi)*192, isbf);
    r = s * (1.f/128.f);
  } else {
    float mx = -3.4e38f;
    for (int hi=0; hi<16; hi++)
      #pragma unroll
      for (int wi=0; wi<8; wi++)
        mx = fmaxf(mx, ld1(qkv, base + (size_t)(hi*128 + wi)*192, isbf));
    r = mx;
  }
  poolq[((size_t)b*128 + n)*192 + c] = f2bf(r * SCALE);
}

// ---------------- attention: one block per (window, batch, head) ----------------
__global__ __launch_bounds__(256)
void attn_kernel(const void* __restrict__ qkv,
                 const unsigned short* __restrict__ poolq,
                 const void* __restrict__ mask,
                 const float* __restrict__ rpb,
                 void* __restrict__ out)
{
  const int isbf = detect_bf16(qkv);
  const int iw = blockIdx.x, b = blockIdx.y, head = blockIdx.z;
  const int hb = iw >> 3, wb = iw & 7;     // window: h in [hb*8,+8), w in [wb*16,+16)
  const int qb = iw & 7;                   // torch .repeat quirk: pooled-q batch = iw % 8
  const int tid = threadIdx.x;
  const int lane = tid & 63, wv = tid >> 6;
  const int quad = lane >> 4, c16 = lane & 15;

  __shared__ unsigned short Vt[32][136];   // V transposed: Vt[d][j]
  __shared__ unsigned short Pl[4][32][136];

  // ---- stage V transposed into LDS ----
  {
    const int row = tid >> 1;              // token j in window
    const int half = (tid & 1) << 4;       // d offset 0 or 16
    const size_t idx = VOFF
      + ((size_t)((b*128 + hb*8 + (row>>4))*128 + wb*16 + (row&15)))*192 + head*32 + half;
    short8 a = ld8(qkv, idx, isbf);
    short8 c = ld8(qkv, idx + 8, isbf);
    #pragma unroll
    for (int t=0;t<8;t++){
      Vt[half + t][row]     = (unsigned short)a[t];
      Vt[half + 8 + t][row] = (unsigned short)c[t];
    }
  }
  __syncthreads();

  // ---- S = Q*K^T ----
  f32x4 acc[2][8];
  {
    const unsigned short* qrow0 = poolq + ((size_t)(qb*128 + wv*32 + c16))*192 + head*32 + quad*8;
    short8 qf0 = *(const short8*)qrow0;
    short8 qf1 = *(const short8*)(qrow0 + (size_t)16*192);
    const size_t kidx = KOFF
      + ((size_t)((b*128 + hb*8)*128 + wb*16 + c16))*192 + head*32 + quad*8;
    f32x4 z = {0.f, 0.f, 0.f, 0.f};
    #pragma unroll
    for (int tj=0; tj<8; tj++){
      short8 kf = ld8(qkv, kidx + (size_t)tj*24576, isbf);  // +tj on h axis within window
      acc[0][tj] = __builtin_amdgcn_mfma_f32_16x16x32_bf16(qf0, kf, z, 0, 0, 0);
      acc[1][tj] = __builtin_amdgcn_mfma_f32_16x16x32_bf16(qf1, kf, z, 0, 0, 0);
    }
  }

  // ---- add rpb + mask (C layout: row = quad*4+r, col = c16) ----
  {
    const float* rp = rpb + head*16384;
    const size_t moff = (size_t)iw*16384;
    #pragma unroll
    for (int ti=0; ti<2; ti++){
      #pragma unroll
      for (int r=0; r<4; r++){
        const int i = wv*32 + ti*16 + quad*4 + r;
        const int rowoff = i*128 + c16;
        #pragma unroll
        for (int tj=0; tj<8; tj++)
          acc[ti][tj][r] += rp[rowoff + tj*16] + ld1(mask, moff + rowoff + tj*16, isbf);
      }
    }
  }

  // ---- softmax per row + write normalized P (bf16) to per-wave LDS ----
  #pragma unroll
  for (int ti=0; ti<2; ti++){
    #pragma unroll
    for (int r=0; r<4; r++){
      float mx = acc[ti][0][r];
      #pragma unroll
      for (int tj=1; tj<8; tj++) mx = fmaxf(mx, acc[ti][tj][r]);
      #pragma unroll
      for (int off=1; off<16; off<<=1) mx = fmaxf(mx, __shfl_xor(mx, off));
      float s = 0.f;
      #pragma unroll
      for (int tj=0; tj<8; tj++){
        float p = __expf(acc[ti][tj][r] - mx);
        acc[ti][tj][r] = p;
        s += p;
      }
      #pragma unroll
      for (int off=1; off<16; off<<=1) s += __shfl_xor(s, off);
      const float rinv = 1.0f / s;
      const int prow = ti*16 + quad*4 + r;
      #pragma unroll
      for (int tj=0; tj<8; tj++)
        Pl[wv][prow][tj*16 + c16] = f2bf(acc[ti][tj][r] * rinv);
    }
  }
  __syncthreads();   // defensive: order Pl writes before reads

  // ---- O = P*V ----
  short8 vf[2][4];
  #pragma unroll
  for (int dt=0; dt<2; dt++)
    #pragma unroll
    for (int jt=0; jt<4; jt++)
      vf[dt][jt] = *(const short8*)&Vt[dt*16 + c16][jt*32 + quad*8];

  f32x4 o[2][2];
  #pragma unroll
  for (int ti=0; ti<2; ti++)
    #pragma unroll
    for (int dt=0; dt<2; dt++){
      f32x4 z = {0.f, 0.f, 0.f, 0.f};
      o[ti][dt] = z;
    }
  #pragma unroll
  for (int ti=0; ti<2; ti++){
    #pragma unroll
    for (int jt=0; jt<4; jt++){
      short8 pf = *(const short8*)&Pl[wv][ti*16 + c16][jt*32 + quad*8];
      o[ti][0] = __builtin_amdgcn_mfma_f32_16x16x32_bf16(pf, vf[0][jt], o[ti][0], 0, 0, 0);
      o[ti][1] = __builtin_amdgcn_mfma_f32_16x16x32_bf16(pf, vf[1][jt], o[ti][1], 0, 0, 0);
    }
  }

  // ---- store (windows2img) ----
  #pragma unroll
  for (int ti=0; ti<2; ti++){
    #pragma unroll
    for (int r=0; r<4; r++){
      const int i = wv*32 + ti*16 + quad*4 + r;
      const int hh = hb*8 + (i>>4), ww = wb*16 + (i&15);
      const size_t oidx = ((size_t)((b*128 + hh)*128 + ww))*192 + head*32 + c16;
      st1(out, oidx,      o[ti][0][r], isbf);
      st1(out, oidx + 16, o[ti][1][r], isbf);
    }
  }
}

extern "C" void kernel_launch(void* const* d_in, const int* in_sizes, int n_in,
                              void* d_out, int out_size, void* d_ws, size_t ws_size,
                              hipStream_t stream)
{
  const void* qkv  = d_in[0];
  const void* mask = d_in[1];
  const int* rel_idx = (const int*)d_in[17];

  float* pos_table = (float*)d_ws;                                        // 11160 B
  float* rpb = (float*)((char*)d_ws + 12288);                             // 393216 B
  unsigned short* poolq = (unsigned short*)((char*)d_ws + 12288 + 393216);// 393216 B

  posmlp_kernel<<<1, 512, 0, stream>>>(qkv, d_in[16],
      d_in[2], d_in[3], d_in[4], d_in[5], d_in[6], d_in[7],
      d_in[8], d_in[9], d_in[10], d_in[11], d_in[12], d_in[13],
      d_in[14], d_in[15], pos_table);
  gather_kernel<<<128, 128, 0, stream>>>(rel_idx, pos_table, rpb);
  pool_kernel<<<dim3(128, 8), 192, 0, stream>>>(qkv, poolq);
  attn_kernel<<<dim3(128, 8, 6), 256, 0, stream>>>(qkv, poolq, mask, rpb, d_out);
}

// Round 3
// 812.203 us; speedup vs baseline: 1.0795x; 1.0795x over previous
//
#include <hip/hip_runtime.h>
#include <cstdint>
#include <cstddef>

typedef __attribute__((ext_vector_type(8))) short short8;
typedef __attribute__((ext_vector_type(4))) float f32x4;

#define SCALE 0.17677669529663687f
#define KOFF 25165824UL
#define VOFF 50331648UL

__device__ __forceinline__ float bf2f(unsigned short u){
  union { unsigned int i; float f; } x; x.i = ((unsigned int)u) << 16; return x.f;
}
__device__ __forceinline__ unsigned short f2bf(float f){
  union { float f; unsigned int i; } x; x.f = f;
  unsigned int u = x.i;
  unsigned int r = u + 0x7fffu + ((u >> 16) & 1u);
  return (unsigned short)(r >> 16);
}

// Detect whether external float tensors are stored as bf16 (1) or fp32 (0).
__device__ __forceinline__ int detect_bf16(const void* probe){
  const unsigned short* p = (const unsigned short*)probe;
  int ok = 1;
  #pragma unroll
  for (int i = 0; i < 32; i++){
    unsigned short u = p[2*i];
    int e = (u >> 7) & 0xFF;
    ok &= (e >= 0x60 && e <= 0x90) ? 1 : 0;
  }
  return ok;
}

__device__ __forceinline__ float ld1(const void* p, size_t i, int isbf){
  return isbf ? bf2f(((const unsigned short*)p)[i]) : ((const float*)p)[i];
}
// 8 consecutive elements (i % 8 == 0) -> bf16 frag (RTE conversion on fp32 path)
__device__ __forceinline__ short8 ld8(const void* p, size_t i, int isbf){
  short8 r;
  if (isbf){
    r = *(const short8*)((const unsigned short*)p + i);
  } else {
    const float4* f = (const float4*)((const float*)p + i);
    float4 u0 = f[0], u1 = f[1];
    r[0] = (short)f2bf(u0.x); r[1] = (short)f2bf(u0.y);
    r[2] = (short)f2bf(u0.z); r[3] = (short)f2bf(u0.w);
    r[4] = (short)f2bf(u1.x); r[5] = (short)f2bf(u1.y);
    r[6] = (short)f2bf(u1.z); r[7] = (short)f2bf(u1.w);
  }
  return r;
}
// 4 consecutive elements (i % 4 == 0) -> float4
__device__ __forceinline__ float4 ld4(const void* p, size_t i, int isbf){
  if (!isbf) return *(const float4*)((const float*)p + i);
  const unsigned short* u = (const unsigned short*)p + i;
  uint2 w = *(const uint2*)u;
  float4 r;
  r.x = bf2f((unsigned short)(w.x & 0xffffu)); r.y = bf2f((unsigned short)(w.x >> 16));
  r.z = bf2f((unsigned short)(w.y & 0xffffu)); r.w = bf2f((unsigned short)(w.y >> 16));
  return r;
}

// ---------------- DynamicPosBias MLP: [465,2] -> [465,6] (fp32 out) ----------------
__global__ void posmlp_kernel(const void* __restrict__ probe,
    const void* __restrict__ rpe,
    const void* __restrict__ w0, const void* __restrict__ b0,
    const void* __restrict__ g1, const void* __restrict__ be1,
    const void* __restrict__ w1, const void* __restrict__ bb1,
    const void* __restrict__ g2, const void* __restrict__ be2,
    const void* __restrict__ w2, const void* __restrict__ bb2,
    const void* __restrict__ g3, const void* __restrict__ be3,
    const void* __restrict__ w3, const void* __restrict__ bb3,
    float* __restrict__ pos_table)
{
  const int isbf = detect_bf16(probe);
  int r = blockIdx.x * blockDim.x + threadIdx.x;
  if (r >= 465) return;
  float x0 = ld1(rpe, 2*r, isbf), x1 = ld1(rpe, 2*r+1, isbf);
  float h[12], y[12];
  #pragma unroll
  for (int j=0;j<12;j++) h[j] = x0*ld1(w0,j,isbf) + x1*ld1(w0,12+j,isbf) + ld1(b0,j,isbf);

  {
    float m=0.f;
    #pragma unroll
    for (int j=0;j<12;j++) m += h[j];
    m *= (1.f/12.f);
    float v=0.f;
    #pragma unroll
    for (int j=0;j<12;j++){ float d=h[j]-m; v += d*d; }
    v *= (1.f/12.f);
    float rs = 1.0f/sqrtf(v + 1e-5f);
    #pragma unroll
    for (int j=0;j<12;j++) y[j] = fmaxf((h[j]-m)*rs*ld1(g1,j,isbf) + ld1(be1,j,isbf), 0.f);
    #pragma unroll
    for (int j=0;j<12;j++){
      float s = ld1(bb1,j,isbf);
      #pragma unroll
      for (int i=0;i<12;i++) s += y[i]*ld1(w1,i*12+j,isbf);
      h[j] = s;
    }
  }
  {
    float m=0.f;
    #pragma unroll
    for (int j=0;j<12;j++) m += h[j];
    m *= (1.f/12.f);
    float v=0.f;
    #pragma unroll
    for (int j=0;j<12;j++){ float d=h[j]-m; v += d*d; }
    v *= (1.f/12.f);
    float rs = 1.0f/sqrtf(v + 1e-5f);
    #pragma unroll
    for (int j=0;j<12;j++) y[j] = fmaxf((h[j]-m)*rs*ld1(g2,j,isbf) + ld1(be2,j,isbf), 0.f);
    #pragma unroll
    for (int j=0;j<12;j++){
      float s = ld1(bb2,j,isbf);
      #pragma unroll
      for (int i=0;i<12;i++) s += y[i]*ld1(w2,i*12+j,isbf);
      h[j] = s;
    }
  }
  {
    float m=0.f;
    #pragma unroll
    for (int j=0;j<12;j++) m += h[j];
    m *= (1.f/12.f);
    float v=0.f;
    #pragma unroll
    for (int j=0;j<12;j++){ float d=h[j]-m; v += d*d; }
    v *= (1.f/12.f);
    float rs = 1.0f/sqrtf(v + 1e-5f);
    #pragma unroll
    for (int j=0;j<12;j++) y[j] = fmaxf((h[j]-m)*rs*ld1(g3,j,isbf) + ld1(be3,j,isbf), 0.f);
    #pragma unroll
    for (int o=0;o<6;o++){
      float s = ld1(bb3,o,isbf);
      #pragma unroll
      for (int i=0;i<12;i++) s += y[i]*ld1(w3,i*6+o,isbf);
      pos_table[r*6+o] = s;
    }
  }
}

// ---------------- gather (native order): rpbN[h][m][n] = pos[rel[m][n]][h], bf16 ----------------
__global__ void gatherN_kernel(const int* __restrict__ rel_idx,
                               const float* __restrict__ pos_table,
                               unsigned short* __restrict__ rpbN)
{
  const int idx = blockIdx.x * 256 + threadIdx.x;   // 0..16383 over m*128+n
  const int h = blockIdx.y;
  rpbN[h*16384 + idx] = f2bf(pos_table[rel_idx[idx]*6 + h]);
}

// ---------------- pooled query: avg (c<96) / max (c>=96), *scale, bf16 out ----------------
__global__ void pool_kernel(const void* __restrict__ qkv,
                            unsigned short* __restrict__ poolq)
{
  const int isbf = detect_bf16(qkv);
  const int b = blockIdx.y;
  const int n = blockIdx.x;            // n = ph*16 + pw
  const int t = threadIdx.x;           // 0..191
  const int cg = t % 48, sub = t / 48; // 48 float4 channel groups, 4 token subsets
  const int ph = n >> 4, pw = n & 15;
  const size_t cell = ((size_t)(b*16384 + ph*16*128 + pw*8))*192 + cg*4;
  const bool avg = (cg < 24);
  float4 acc;
  if (avg){ acc.x=0.f; acc.y=0.f; acc.z=0.f; acc.w=0.f; }
  else    { acc.x=-3.4e38f; acc.y=-3.4e38f; acc.z=-3.4e38f; acc.w=-3.4e38f; }
  #pragma unroll
  for (int hh=0; hh<4; hh++){
    const int hi = sub*4 + hh;
    #pragma unroll
    for (int wi=0; wi<8; wi++){
      float4 xv = ld4(qkv, cell + (size_t)(hi*128 + wi)*192, isbf);
      if (avg){ acc.x+=xv.x; acc.y+=xv.y; acc.z+=xv.z; acc.w+=xv.w; }
      else { acc.x=fmaxf(acc.x,xv.x); acc.y=fmaxf(acc.y,xv.y);
             acc.z=fmaxf(acc.z,xv.z); acc.w=fmaxf(acc.w,xv.w); }
    }
  }
  __shared__ float4 pr[4][48];
  pr[sub][cg] = acc;
  __syncthreads();
  if (sub == 0){
    #pragma unroll
    for (int s=1; s<4; s++){
      float4 xv = pr[s][cg];
      if (avg){ acc.x+=xv.x; acc.y+=xv.y; acc.z+=xv.z; acc.w+=xv.w; }
      else { acc.x=fmaxf(acc.x,xv.x); acc.y=fmaxf(acc.y,xv.y);
             acc.z=fmaxf(acc.z,xv.z); acc.w=fmaxf(acc.w,xv.w); }
    }
    if (avg){ acc.x*=(1.f/128.f); acc.y*=(1.f/128.f); acc.z*=(1.f/128.f); acc.w*=(1.f/128.f); }
    unsigned int lo = (unsigned int)f2bf(acc.x*SCALE) | ((unsigned int)f2bf(acc.y*SCALE) << 16);
    unsigned int hi = (unsigned int)f2bf(acc.z*SCALE) | ((unsigned int)f2bf(acc.w*SCALE) << 16);
    uint2 st; st.x = lo; st.y = hi;
    *(uint2*)(poolq + ((size_t)b*128 + n)*192 + cg*4) = st;
  }
}

// ---------------- attention (S^T orientation): one block per (window, batch, head) ----------------
__global__ __launch_bounds__(256)
void attn_kernel(const void* __restrict__ qkv,
                 const unsigned short* __restrict__ poolq,
                 const void* __restrict__ mask,
                 const unsigned short* __restrict__ rpbN,
                 void* __restrict__ out)
{
  const int isbf = detect_bf16(qkv);
  const int iw = blockIdx.x, b = blockIdx.y, head = blockIdx.z;
  const int hb = iw >> 3, wb = iw & 7;   // window: h in [hb*8,+8), w in [wb*16,+16)
  const int qb = iw & 7;                 // torch .repeat quirk: pooled-q batch = iw % 8
  const int tid = threadIdx.x;
  const int lane = tid & 63, wv = tid >> 6;
  const int quad = lane >> 4, c16 = lane & 15;

  __shared__ unsigned short Vt[32][136];   // V^T: Vt[d][token]           (8704 B)
  __shared__ float redM[4][128];           // per-wave col max            (2048 B)
  __shared__ float redS[4][128];           // per-wave col sum            (2048 B)
  __shared__ unsigned short Pl[128][136];  // P[m][n]; start reused as Kt (34816 B)
  unsigned short* Kt = &Pl[0][0];          // K staged row-major, pitch 40 (10240 B)

  // ---- stage Kt (each wave stages exactly its own 32 tokens) and Vt ----
  {
    const int tok = tid >> 1;            // token index in window (0..127); wave wv owns [wv*32, wv*32+32)
    const int dh  = (tid & 1) << 4;      // dim half 0 / 16
    const size_t rowidx = ((size_t)((b*128 + hb*8 + (tok>>4))*128 + wb*16 + (tok&15)))*192 + head*32 + dh;
    short8 k0 = ld8(qkv, KOFF + rowidx, isbf);
    short8 k1 = ld8(qkv, KOFF + rowidx + 8, isbf);
    *(short8*)(Kt + tok*40 + dh)     = k0;
    *(short8*)(Kt + tok*40 + dh + 8) = k1;
    short8 v0 = ld8(qkv, VOFF + rowidx, isbf);
    short8 v1 = ld8(qkv, VOFF + rowidx + 8, isbf);
    #pragma unroll
    for (int u=0; u<8; u++){
      Vt[dh + u][tok]     = (unsigned short)v0[u];
      Vt[dh + 8 + u][tok] = (unsigned short)v1[u];
    }
  }
  // no barrier needed: QK below reads only this wave's Kt rows

  // ---- T = K·Q^T tiles: D[i=token n][j=query m]; acc[tn][tm] ----
  short8 kA[2];
  #pragma unroll
  for (int tn=0; tn<2; tn++)
    kA[tn] = *(const short8*)(Kt + (wv*32 + tn*16 + c16)*40 + quad*8);

  f32x4 acc[2][8];
  #pragma unroll
  for (int tm=0; tm<8; tm++){
    short8 qf = *(const short8*)(poolq + ((size_t)(qb*128 + tm*16 + c16))*192 + head*32 + quad*8);
    f32x4 z = {0.f, 0.f, 0.f, 0.f};
    acc[0][tm] = __builtin_amdgcn_mfma_f32_16x16x32_bf16(kA[0], qf, z, 0, 0, 0);
    acc[1][tm] = __builtin_amdgcn_mfma_f32_16x16x32_bf16(kA[1], qf, z, 0, 0, 0);
  }

  // ---- bias add via identity-A MFMA: D[i][j] += B[j][i]; B[j][k] = bias[mbase+j][nbase+k] ----
  short8 idf;
  #pragma unroll
  for (int j=0; j<8; j++) idf[j] = (short)((quad*8 + j == c16) ? 0x3F80 : 0);

  #pragma unroll
  for (int tn=0; tn<2; tn++){
    const int nb = wv*32 + tn*16 + (quad&1)*8;  // quads 2,3 reload k<16 rows; A is zero there
    #pragma unroll
    for (int tm=0; tm<8; tm++){
      const int mrow = tm*16 + c16;
      short8 mfg;
      if (isbf){
        mfg = *(const short8*)((const unsigned short*)mask + (size_t)iw*16384 + mrow*128 + nb);
      } else {
        const float* mp = (const float*)mask + (size_t)iw*16384 + mrow*128 + nb;
        float4 a = *(const float4*)mp;
        float4 c = *(const float4*)(mp + 4);
        mfg[0] = (short)(__float_as_uint(a.x) >> 16); mfg[1] = (short)(__float_as_uint(a.y) >> 16);
        mfg[2] = (short)(__float_as_uint(a.z) >> 16); mfg[3] = (short)(__float_as_uint(a.w) >> 16);
        mfg[4] = (short)(__float_as_uint(c.x) >> 16); mfg[5] = (short)(__float_as_uint(c.y) >> 16);
        mfg[6] = (short)(__float_as_uint(c.z) >> 16); mfg[7] = (short)(__float_as_uint(c.w) >> 16);
      }
      short8 rfg = *(const short8*)(rpbN + (size_t)head*16384 + mrow*128 + nb);
      acc[tn][tm] = __builtin_amdgcn_mfma_f32_16x16x32_bf16(idf, mfg, acc[tn][tm], 0, 0, 0);
      acc[tn][tm] = __builtin_amdgcn_mfma_f32_16x16x32_bf16(idf, rfg, acc[tn][tm], 0, 0, 0);
    }
  }

  // ---- cross-wave softmax over rows (tokens) per column (query) ----
  float wmax[8], wsum[8], wsc[8];
  #pragma unroll
  for (int tm=0; tm<8; tm++){
    float mx = acc[0][tm][0];
    #pragma unroll
    for (int tn=0; tn<2; tn++)
      #pragma unroll
      for (int r=0; r<4; r++) mx = fmaxf(mx, acc[tn][tm][r]);
    mx = fmaxf(mx, __shfl_xor(mx, 16));
    mx = fmaxf(mx, __shfl_xor(mx, 32));
    wmax[tm] = mx;
  }
  #pragma unroll
  for (int tm=0; tm<8; tm++){
    float s = 0.f;
    #pragma unroll
    for (int tn=0; tn<2; tn++)
      #pragma unroll
      for (int r=0; r<4; r++){
        float p = __expf(acc[tn][tm][r] - wmax[tm]);
        acc[tn][tm][r] = p;
        s += p;
      }
    s += __shfl_xor(s, 16);
    s += __shfl_xor(s, 32);
    wsum[tm] = s;
  }
  if (quad == 0){
    #pragma unroll
    for (int tm=0; tm<8; tm++){
      redM[wv][tm*16 + c16] = wmax[tm];
      redS[wv][tm*16 + c16] = wsum[tm];
    }
  }
  __syncthreads();   // BARRIER 1: red visible; also all QK done -> Kt region free
  #pragma unroll
  for (int tm=0; tm<8; tm++){
    const int col = tm*16 + c16;
    float m0 = redM[0][col], m1 = redM[1][col], m2 = redM[2][col], m3 = redM[3][col];
    float M = fmaxf(fmaxf(m0, m1), fmaxf(m2, m3));
    float S = redS[0][col]*__expf(m0 - M) + redS[1][col]*__expf(m1 - M)
            + redS[2][col]*__expf(m2 - M) + redS[3][col]*__expf(m3 - M);
    wsc[tm] = __expf(wmax[tm] - M) / S;
  }
  // write P[m][n] (bf16, truncation: p in [0,1], err ~2^-9 rel)
  #pragma unroll
  for (int tn=0; tn<2; tn++)
    #pragma unroll
    for (int tm=0; tm<8; tm++)
      #pragma unroll
      for (int r=0; r<4; r++)
        Pl[tm*16 + c16][wv*32 + tn*16 + quad*4 + r] =
          (unsigned short)(__float_as_uint(acc[tn][tm][r] * wsc[tm]) >> 16);
  __syncthreads();   // BARRIER 2: Pl + Vt visible to all waves

  // ---- O^T = V^T · P^T : o[tmo][dt]; D[i=d][j=m] ----
  f32x4 o[2][2];
  #pragma unroll
  for (int a=0; a<2; a++)
    #pragma unroll
    for (int d=0; d<2; d++){ f32x4 z = {0.f,0.f,0.f,0.f}; o[a][d] = z; }
  #pragma unroll
  for (int jt=0; jt<4; jt++){
    short8 vA0 = *(const short8*)&Vt[c16][jt*32 + quad*8];
    short8 vA1 = *(const short8*)&Vt[16 + c16][jt*32 + quad*8];
    short8 p0  = *(const short8*)&Pl[wv*32 + c16][jt*32 + quad*8];
    short8 p1  = *(const short8*)&Pl[wv*32 + 16 + c16][jt*32 + quad*8];
    o[0][0] = __builtin_amdgcn_mfma_f32_16x16x32_bf16(vA0, p0, o[0][0], 0, 0, 0);
    o[0][1] = __builtin_amdgcn_mfma_f32_16x16x32_bf16(vA1, p0, o[0][1], 0, 0, 0);
    o[1][0] = __builtin_amdgcn_mfma_f32_16x16x32_bf16(vA0, p1, o[1][0], 0, 0, 0);
    o[1][1] = __builtin_amdgcn_mfma_f32_16x16x32_bf16(vA1, p1, o[1][1], 0, 0, 0);
  }
  __syncthreads();   // BARRIER 3: all PV reads of Pl done before fp32 reuse (also a type-alias fence)

  // ---- epilogue: transpose O^T (C-layout) through LDS, vector stores ----
  float* Plf = (float*)(&Pl[0][0] + (size_t)wv*32*136);   // per-wave 8704 B region; pitch 36 floats
  #pragma unroll
  for (int tmo=0; tmo<2; tmo++)
    #pragma unroll
    for (int dt=0; dt<2; dt++)
      #pragma unroll
      for (int r=0; r<4; r++)
        Plf[(tmo*16 + c16)*36 + dt*16 + quad*4 + r] = o[tmo][dt][r];
  // wave-private region; in-wave DS ordering suffices
  {
    const int tk = lane >> 1;            // local output token (query) 0..31
    const int h2 = lane & 1;             // dim half
    const int token = wv*32 + tk;
    const int hh = hb*8 + (token >> 4), ww = wb*16 + (token & 15);
    const size_t obase = ((size_t)((b*128 + hh)*128 + ww))*192 + head*32 + h2*16;
    #pragma unroll
    for (int it=0; it<4; it++){
      float4 val = *(const float4*)&Plf[tk*36 + h2*16 + it*4];
      if (isbf){
        unsigned int lo = (unsigned int)f2bf(val.x) | ((unsigned int)f2bf(val.y) << 16);
        unsigned int hi = (unsigned int)f2bf(val.z) | ((unsigned int)f2bf(val.w) << 16);
        uint2 st; st.x = lo; st.y = hi;
        *(uint2*)((unsigned short*)out + obase + it*4) = st;
      } else {
        *(float4*)((float*)out + obase + it*4) = val;
      }
    }
  }
}

extern "C" void kernel_launch(void* const* d_in, const int* in_sizes, int n_in,
                              void* d_out, int out_size, void* d_ws, size_t ws_size,
                              hipStream_t stream)
{
  const void* qkv  = d_in[0];
  const void* mask = d_in[1];
  const int* rel_idx = (const int*)d_in[17];

  float* pos_table     = (float*)d_ws;                                   // 11160 B
  unsigned short* rpbN = (unsigned short*)((char*)d_ws + 12288);         // 6*16384*2 = 196608 B
  unsigned short* poolq= (unsigned short*)((char*)d_ws + 12288 + 196608);// 8*128*192*2 = 393216 B? no: 196608 B

  posmlp_kernel<<<1, 512, 0, stream>>>(qkv, d_in[16],
      d_in[2], d_in[3], d_in[4], d_in[5], d_in[6], d_in[7],
      d_in[8], d_in[9], d_in[10], d_in[11], d_in[12], d_in[13],
      d_in[14], d_in[15], pos_table);
  gatherN_kernel<<<dim3(64, 6), 256, 0, stream>>>(rel_idx, pos_table, rpbN);
  pool_kernel<<<dim3(128, 8), 192, 0, stream>>>(qkv, poolq);
  attn_kernel<<<dim3(128, 8, 6), 256, 0, stream>>>(qkv, poolq, mask, rpbN, d_out);
}